// Round 1
// baseline (17075.447 us; speedup 1.0000x reference)
//
#include <hip/hip_runtime.h>
#include <hip/hip_bf16.h>
#include <math.h>

#define DEVI static __device__ __forceinline__

namespace {
constexpr int B = 32, T = 512, H = 1024, E = 300, V = 32000, S = 50;
constexpr int KX = E + H;  // 1324
}

DEVI float fast_tanh(float x) { return 1.0f - 2.0f / (__expf(2.0f * x) + 1.0f); }
DEVI float sigmoidf_(float x) { return 1.0f / (1.0f + __expf(-x)); }
DEVI float dot4(float4 a, float4 b) { return a.x*b.x + a.y*b.y + a.z*b.z + a.w*b.w; }

// ---- initial state: merge bidirectional encoder halves --------------------
__global__ void k_init(const float* __restrict__ enc_h, const float* __restrict__ enc_c,
                       float* __restrict__ h0, float* __restrict__ c0) {
  int idx = blockIdx.x * blockDim.x + threadIdx.x;  // over 2*B*H
  if (idx >= 2 * B * H) return;
  int l = idx / (B * H), r = idx % (B * H);
  int b = r / H, hh = r % H;
  int half = hh / (H / 2), hr = hh % (H / 2);
  int src = (2 * l + half) * B * (H / 2) + b * (H / 2) + hr;
  h0[idx] = enc_h[src];
  c0[idx] = enc_c[src];
}

// ---- enc_proj[m][n] = sum_k enc_out[m][k] * attn_W[n][H+k] + attn_b[n] ----
// m in [0, B*T), n in [0, H).  Tiled 64x64x16 f32 GEMM.
__global__ __launch_bounds__(256) void k_encproj(const float* __restrict__ enc_out,
    const float* __restrict__ attn_W, const float* __restrict__ attn_b,
    float* __restrict__ enc_proj) {
  __shared__ float As[16][66];
  __shared__ float Bs[16][66];
  int m0 = blockIdx.y * 64;
  int n0 = blockIdx.x * 64;
  int tid = threadIdx.x;
  int tx = tid & 15, ty = tid >> 4;
  float acc[4][4] = {};
  for (int k0 = 0; k0 < H; k0 += 16) {
#pragma unroll
    for (int i = 0; i < 4; i++) {
      int e = tid + i * 256;
      int mm = e >> 4, kk = e & 15;
      As[kk][mm] = enc_out[(size_t)(m0 + mm) * H + k0 + kk];
      Bs[kk][mm] = attn_W[(size_t)(n0 + mm) * (2 * H) + H + k0 + kk];
    }
    __syncthreads();
#pragma unroll
    for (int kk = 0; kk < 16; kk++) {
      float a[4], bb[4];
#pragma unroll
      for (int i = 0; i < 4; i++) a[i] = As[kk][ty + 16 * i];
#pragma unroll
      for (int j = 0; j < 4; j++) bb[j] = Bs[kk][tx + 16 * j];
#pragma unroll
      for (int i = 0; i < 4; i++)
#pragma unroll
        for (int j = 0; j < 4; j++) acc[i][j] += a[i] * bb[j];
    }
    __syncthreads();
  }
#pragma unroll
  for (int i = 0; i < 4; i++) {
    int m = m0 + ty + 16 * i;
#pragma unroll
    for (int j = 0; j < 4; j++) {
      int n = n0 + tx + 16 * j;
      enc_proj[(size_t)m * H + n] = acc[i][j] + attn_b[n];
    }
  }
}

// ---- generic batch-32 GEMV: out[b][n] = bias[n] + sum_k W[n*ldW+k]*X[b][k]
// K must be a multiple of 256. Block = 256 thr = 4 waves; 8 rows per block;
// wave w: rowgroup = w&1 (4 rows), bhalf = w>>1 (16 batches).
__global__ __launch_bounds__(256) void k_gemv(
    const float* __restrict__ W, int ldW, int K,
    const float* __restrict__ X,
    const float* __restrict__ bias,
    float* __restrict__ out, int ldOut) {
  __shared__ float Xsh[B][256];
  int tid = threadIdx.x;
  int lane = tid & 63, wv = tid >> 6;
  int rg = wv & 1, bh = wv >> 1;
  int n0 = blockIdx.x * 8 + rg * 4;
  float acc[4][16];
#pragma unroll
  for (int r = 0; r < 4; r++)
#pragma unroll
    for (int b = 0; b < 16; b++) acc[r][b] = 0.f;

  for (int kc = 0; kc < K; kc += 256) {
    __syncthreads();
    for (int i4 = tid; i4 < B * 64; i4 += 256) {
      int bb = i4 >> 6, j4 = i4 & 63;
      *(float4*)&Xsh[bb][j4 * 4] = *(const float4*)&X[(size_t)bb * K + kc + j4 * 4];
    }
    __syncthreads();
    int kl = kc + lane * 4;
    float4 w4[4];
#pragma unroll
    for (int r = 0; r < 4; r++)
      w4[r] = *(const float4*)&W[(size_t)(n0 + r) * ldW + kl];
#pragma unroll
    for (int b = 0; b < 16; b++) {
      float4 x4 = *(const float4*)&Xsh[bh * 16 + b][lane * 4];
#pragma unroll
      for (int r = 0; r < 4; r++) acc[r][b] += dot4(w4[r], x4);
    }
  }
  float outv[4];
#pragma unroll
  for (int r = 0; r < 4; r++) {
#pragma unroll
    for (int b = 0; b < 16; b++) {
      float s = acc[r][b];
#pragma unroll
      for (int off = 32; off; off >>= 1) s += __shfl_xor(s, off, 64);
      if ((lane & 15) == b) outv[r] = s;
    }
  }
  if (lane < 16) {
    int b = bh * 16 + lane;
#pragma unroll
    for (int r = 0; r < 4; r++) {
      int n = n0 + r;
      float val = outv[r];
      if (bias) val += bias[n];
      out[(size_t)b * ldOut + n] = val;
    }
  }
}

// ---- fused LSTM layer: dual GEMV (Wih@X1 + Whh@hprev) + cell, writes h/c --
// Block handles 2 hidden columns n2; wave's 4 rows = the 4 gates (i,f,g,o).
__global__ __launch_bounds__(256) void k_lstm(
    const float* __restrict__ Wih, int K1, const float* __restrict__ X1,
    const float* __restrict__ Whh, const float* __restrict__ hprev,
    const float* __restrict__ bih, const float* __restrict__ bhh,
    const float* __restrict__ cprev,
    float* __restrict__ hnext, float* __restrict__ cnext) {
  __shared__ float Xsh[B][256];
  int tid = threadIdx.x;
  int lane = tid & 63, wv = tid >> 6;
  int rg = wv & 1, bh = wv >> 1;
  int n2 = blockIdx.x * 2 + rg;
  float acc[4][16];
#pragma unroll
  for (int r = 0; r < 4; r++)
#pragma unroll
    for (int b = 0; b < 16; b++) acc[r][b] = 0.f;

  const float* Wp[2] = {Wih, Whh};
  const float* Xp[2] = {X1, hprev};
  int Kp[2] = {K1, H};
  for (int ph = 0; ph < 2; ph++) {
    const float* Wm = Wp[ph];
    const float* Xm = Xp[ph];
    int K = Kp[ph];
    for (int kc = 0; kc < K; kc += 256) {
      __syncthreads();
      for (int i4 = tid; i4 < B * 64; i4 += 256) {
        int bb = i4 >> 6, j4 = i4 & 63;
        int k = kc + j4 * 4;
        float4 val = make_float4(0.f, 0.f, 0.f, 0.f);
        if (k < K) val = *(const float4*)&Xm[(size_t)bb * K + k];
        *(float4*)&Xsh[bb][j4 * 4] = val;
      }
      __syncthreads();
      int kl = kc + lane * 4;
      bool ok = kl < K;
      float4 w4[4];
#pragma unroll
      for (int r = 0; r < 4; r++)
        w4[r] = ok ? *(const float4*)&Wm[(size_t)(r * H + n2) * K + kl]
                   : make_float4(0.f, 0.f, 0.f, 0.f);
#pragma unroll
      for (int b = 0; b < 16; b++) {
        float4 x4 = *(const float4*)&Xsh[bh * 16 + b][lane * 4];
#pragma unroll
        for (int r = 0; r < 4; r++) acc[r][b] += dot4(w4[r], x4);
      }
    }
  }
  float gv[4];
#pragma unroll
  for (int r = 0; r < 4; r++) {
#pragma unroll
    for (int b = 0; b < 16; b++) {
      float s = acc[r][b];
#pragma unroll
      for (int off = 32; off; off >>= 1) s += __shfl_xor(s, off, 64);
      if ((lane & 15) == b) gv[r] = s;
    }
  }
  if (lane < 16) {
    int b = bh * 16 + lane;
    float gi = gv[0] + bih[n2] + bhh[n2];
    float gf = gv[1] + bih[H + n2] + bhh[H + n2];
    float gg = gv[2] + bih[2 * H + n2] + bhh[2 * H + n2];
    float go = gv[3] + bih[3 * H + n2] + bhh[3 * H + n2];
    float i_ = sigmoidf_(gi), f_ = sigmoidf_(gf);
    float g_ = tanhf(gg), o_ = sigmoidf_(go);
    float c2 = f_ * cprev[(size_t)b * H + n2] + i_ * g_;
    float h2 = o_ * tanhf(c2);
    cnext[(size_t)b * H + n2] = c2;
    hnext[(size_t)b * H + n2] = h2;
  }
}

// ---- scores[b][t] = sum_h v[h] * tanh(enc_proj[b,t,h] + hidproj[b,h]) ----
__global__ __launch_bounds__(256) void k_scores(const float* __restrict__ enc_proj,
    const float* __restrict__ hidproj, const float* __restrict__ vvec,
    float* __restrict__ scores) {
  int wid = blockIdx.x * 4 + (threadIdx.x >> 6);  // one wave per (b,t)
  int lane = threadIdx.x & 63;
  int b = wid >> 9;  // T=512
  const float4* ep = (const float4*)enc_proj + (size_t)wid * (H / 4);
  const float4* hp = (const float4*)hidproj + (size_t)b * (H / 4);
  const float4* v4 = (const float4*)vvec;
  float acc = 0.f;
#pragma unroll
  for (int i = 0; i < 4; i++) {  // H/4/64 = 4
    int idx = lane + i * 64;
    float4 e = ep[idx], hh = hp[idx], vv = v4[idx];
    acc += vv.x * fast_tanh(e.x + hh.x);
    acc += vv.y * fast_tanh(e.y + hh.y);
    acc += vv.z * fast_tanh(e.z + hh.z);
    acc += vv.w * fast_tanh(e.w + hh.w);
  }
#pragma unroll
  for (int off = 32; off; off >>= 1) acc += __shfl_xor(acc, off, 64);
  if (lane == 0) scores[wid] = acc;
}

// ---- softmax over T + ctx = aw @ enc_out + embedding gather → xbuf --------
// grid (B, 5): y<4 → ctx h-chunk of 256; y==4 → embedding copy.
__global__ __launch_bounds__(256) void k_ctx(const float* __restrict__ scores,
    const float* __restrict__ enc_out, const float* __restrict__ embedding,
    const int* __restrict__ question, int s, float* __restrict__ xbuf) {
  int b = blockIdx.x;
  int tid = threadIdx.x;
  if (blockIdx.y == 4) {
    int tok = question[b * S + s];
    for (int e = tid; e < E; e += 256)
      xbuf[(size_t)b * KX + e] = embedding[(size_t)tok * E + e];
    return;
  }
  __shared__ float aw[T];
  __shared__ float red[256];
  float m = -1e30f;
  for (int t = tid; t < T; t += 256) m = fmaxf(m, scores[b * T + t]);
  red[tid] = m;
  __syncthreads();
  for (int st = 128; st > 0; st >>= 1) {
    if (tid < st) red[tid] = fmaxf(red[tid], red[tid + st]);
    __syncthreads();
  }
  m = red[0];
  __syncthreads();
  float ssum = 0.f;
  for (int t = tid; t < T; t += 256) {
    float e = __expf(scores[b * T + t] - m);
    aw[t] = e;
    ssum += e;
  }
  red[tid] = ssum;
  __syncthreads();
  for (int st = 128; st > 0; st >>= 1) {
    if (tid < st) red[tid] += red[tid + st];
    __syncthreads();
  }
  float inv = 1.0f / red[0];
  int h = blockIdx.y * 256 + tid;
  const float* eo = enc_out + (size_t)b * T * H + h;
  float a0 = 0.f, a1 = 0.f, a2 = 0.f, a3 = 0.f;
  for (int t = 0; t < T; t += 4) {
    a0 += aw[t + 0] * eo[(size_t)(t + 0) * H];
    a1 += aw[t + 1] * eo[(size_t)(t + 1) * H];
    a2 += aw[t + 2] * eo[(size_t)(t + 2) * H];
    a3 += aw[t + 3] * eo[(size_t)(t + 3) * H];
  }
  xbuf[(size_t)b * KX + E + h] = (a0 + a1 + a2 + a3) * inv;
}

// ---- log_softmax over V, write out[b][s][:] -------------------------------
__global__ __launch_bounds__(1024) void k_logsoftmax(const float* __restrict__ logits,
                                                     float* __restrict__ out, int s) {
  int b = blockIdx.x, tid = threadIdx.x;
  __shared__ float red[1024];
  float m = -1e30f;
  for (int v = tid; v < V; v += 1024) m = fmaxf(m, logits[(size_t)b * V + v]);
  red[tid] = m;
  __syncthreads();
  for (int st = 512; st > 0; st >>= 1) {
    if (tid < st) red[tid] = fmaxf(red[tid], red[tid + st]);
    __syncthreads();
  }
  m = red[0];
  __syncthreads();
  float ssum = 0.f;
  for (int v = tid; v < V; v += 1024) ssum += __expf(logits[(size_t)b * V + v] - m);
  red[tid] = ssum;
  __syncthreads();
  for (int st = 512; st > 0; st >>= 1) {
    if (tid < st) red[tid] += red[tid + st];
    __syncthreads();
  }
  float lse = m + logf(red[0]);
  float* o = out + ((size_t)b * S + s) * V;
  for (int v = tid; v < V; v += 1024) o[v] = logits[(size_t)b * V + v] - lse;
}

extern "C" void kernel_launch(void* const* d_in, const int* in_sizes, int n_in,
                              void* d_out, int out_size, void* d_ws, size_t ws_size,
                              hipStream_t stream) {
  const float* enc_out   = (const float*)d_in[0];
  const float* enc_h     = (const float*)d_in[1];
  const float* enc_c     = (const float*)d_in[2];
  const float* embedding = (const float*)d_in[3];
  const float* attn_W    = (const float*)d_in[4];
  const float* attn_b    = (const float*)d_in[5];
  const float* vvec      = (const float*)d_in[6];
  const float* Wih0      = (const float*)d_in[7];
  const float* Whh0      = (const float*)d_in[8];
  const float* bih0      = (const float*)d_in[9];
  const float* bhh0      = (const float*)d_in[10];
  const float* Wih1      = (const float*)d_in[11];
  const float* Whh1      = (const float*)d_in[12];
  const float* bih1      = (const float*)d_in[13];
  const float* bhh1      = (const float*)d_in[14];
  const float* genW      = (const float*)d_in[15];
  const float* genb      = (const float*)d_in[16];
  const int*   question  = (const int*)d_in[17];
  float* out = (float*)d_out;

  float* p = (float*)d_ws;
  float* enc_proj = p; p += (size_t)B * T * H;      // 16.7M
  float* hbuf = p; p += 2 * 2 * B * H;              // [parity][layer][b][h]
  float* cbuf = p; p += 2 * 2 * B * H;
  float* hidproj = p; p += B * H;
  float* scores = p; p += B * T;
  float* xbuf = p; p += B * KX;
  float* logits = p; p += (size_t)B * V;

  k_init<<<(2 * B * H + 255) / 256, 256, 0, stream>>>(enc_h, enc_c, hbuf, cbuf);
  k_encproj<<<dim3(H / 64, B * T / 64), 256, 0, stream>>>(enc_out, attn_W, attn_b, enc_proj);

  for (int s = 0; s < S; s++) {
    int pp = s & 1, q = pp ^ 1;
    float* h0p = hbuf + (size_t)pp * 2 * B * H;
    float* h1p = h0p + B * H;
    float* h0n = hbuf + (size_t)q * 2 * B * H;
    float* h1n = h0n + B * H;
    float* c0p = cbuf + (size_t)pp * 2 * B * H;
    float* c1p = c0p + B * H;
    float* c0n = cbuf + (size_t)q * 2 * B * H;
    float* c1n = c0n + B * H;

    // hidproj[b][h] = sum_k attn_W[h][k] * h1_prev[b][k]
    k_gemv<<<H / 8, 256, 0, stream>>>(attn_W, 2 * H, H, h1p, nullptr, hidproj, H);
    k_scores<<<B * T / 4, 256, 0, stream>>>(enc_proj, hidproj, vvec, scores);
    k_ctx<<<dim3(B, 5), 256, 0, stream>>>(scores, enc_out, embedding, question, s, xbuf);
    k_lstm<<<H / 2, 256, 0, stream>>>(Wih0, KX, xbuf, Whh0, h0p, bih0, bhh0, c0p, h0n, c0n);
    k_lstm<<<H / 2, 256, 0, stream>>>(Wih1, H, h0n, Whh1, h1p, bih1, bhh1, c1p, h1n, c1n);
    k_gemv<<<V / 8, 256, 0, stream>>>(genW, H, H, h1n, genb, logits, V);
    k_logsoftmax<<<B, 1024, 0, stream>>>(logits, out, s);
  }
}

// Round 2
// 6243.443 us; speedup vs baseline: 2.7349x; 2.7349x over previous
//
#include <hip/hip_runtime.h>
#include <hip/hip_bf16.h>
#include <math.h>

#define DEVI static __device__ __forceinline__

namespace {
constexpr int B = 32, T = 512, H = 1024, E = 300, V = 32000, S = 50;
constexpr int KX = E + H;       // 1324
constexpr int K0 = 2368;        // KX + H + 20 zero-pad  (74 * 32)
constexpr int K1 = 2048;        // H + H                 (64 * 32)
constexpr int MG = V + H;       // 33024 = generator rows + attn-left rows
}

typedef __bf16 bf16x8 __attribute__((ext_vector_type(8)));
typedef float f32x4 __attribute__((ext_vector_type(4)));

DEVI float bf2f(unsigned short u) { union { unsigned int i; float f; } v; v.i = (unsigned int)u << 16; return v.f; }
DEVI unsigned short f2bf(float f) {
  union { float f; unsigned int i; } v; v.f = f;
  unsigned int x = v.i;
  return (unsigned short)((x + 0x7fffu + ((x >> 16) & 1u)) >> 16);
}
#if __has_builtin(__builtin_amdgcn_rcpf)
DEVI float frcp(float x) { return __builtin_amdgcn_rcpf(x); }
#else
DEVI float frcp(float x) { return 1.0f / x; }
#endif
DEVI float sigm(float x) { return frcp(1.0f + __expf(-x)); }
DEVI float tanh_(float x) { return 1.0f - 2.0f * frcp(__expf(2.0f * x) + 1.0f); }

// ===== one-time weight casts ==============================================
__global__ __launch_bounds__(256) void k_cast_gen(const float* __restrict__ genW,
    const float* __restrict__ attn_W, unsigned short* __restrict__ Wbig) {
  size_t i4 = ((size_t)blockIdx.x * 256 + threadIdx.x) * 4;
  if (i4 >= (size_t)MG * H) return;
  int row = (int)(i4 >> 10), k = (int)(i4 & 1023);
  const float* src = row < V ? &genW[((size_t)row << 10) + k]
                             : &attn_W[(size_t)(row - V) * (2 * H) + k];
  float4 v = *(const float4*)src;
  ushort4 o; o.x = f2bf(v.x); o.y = f2bf(v.y); o.z = f2bf(v.z); o.w = f2bf(v.w);
  *(ushort4*)&Wbig[i4] = o;
}

__global__ __launch_bounds__(256) void k_cast_l0(const float* __restrict__ Wih,
    const float* __restrict__ Whh, unsigned short* __restrict__ Wc) {
  int m = blockIdx.x;                       // 4096 rows, m = n*4 + g
  int g = m & 3, n = m >> 2, srow = g * H + n;
  for (int i = threadIdx.x; i < K0 / 4; i += 256) {
    int k = i * 4;
    float4 v;
    if (k < KX) v = *(const float4*)&Wih[(size_t)srow * KX + k];
    else if (k < KX + H) v = *(const float4*)&Whh[(size_t)srow * H + (k - KX)];
    else v = make_float4(0.f, 0.f, 0.f, 0.f);
    ushort4 o; o.x = f2bf(v.x); o.y = f2bf(v.y); o.z = f2bf(v.z); o.w = f2bf(v.w);
    *(ushort4*)&Wc[(size_t)m * K0 + k] = o;
  }
}

__global__ __launch_bounds__(256) void k_cast_l1(const float* __restrict__ Wih,
    const float* __restrict__ Whh, unsigned short* __restrict__ Wc) {
  int m = blockIdx.x;
  int g = m & 3, n = m >> 2, srow = g * H + n;
  for (int i = threadIdx.x; i < K1 / 4; i += 256) {
    int k = i * 4;
    float4 v = (k < H) ? *(const float4*)&Wih[(size_t)srow * H + k]
                       : *(const float4*)&Whh[(size_t)srow * H + (k - H)];
    ushort4 o; o.x = f2bf(v.x); o.y = f2bf(v.y); o.z = f2bf(v.z); o.w = f2bf(v.w);
    *(ushort4*)&Wc[(size_t)m * K1 + k] = o;
  }
}

__global__ void k_bias(const float* bih0, const float* bhh0,
                       const float* bih1, const float* bhh1,
                       float* bc0, float* bc1) {
  int idx = blockIdx.x * 256 + threadIdx.x;
  if (idx < 4096) { int g = idx & 3, n = idx >> 2; bc0[idx] = bih0[g * H + n] + bhh0[g * H + n]; }
  else if (idx < 8192) { int m = idx - 4096; int g = m & 3, n = m >> 2; bc1[m] = bih1[g * H + n] + bhh1[g * H + n]; }
}

__global__ __launch_bounds__(256) void k_cast_enc(const float* __restrict__ src,
                                                  unsigned short* __restrict__ dst) {
  size_t i4 = ((size_t)blockIdx.x * 256 + threadIdx.x) * 4;
  if (i4 >= (size_t)B * T * H) return;
  float4 v = *(const float4*)&src[i4];
  ushort4 o; o.x = f2bf(v.x); o.y = f2bf(v.y); o.z = f2bf(v.z); o.w = f2bf(v.w);
  *(ushort4*)&dst[i4] = o;
}

// ===== initial state =======================================================
__global__ __launch_bounds__(256) void k_init(const float* __restrict__ enc_h,
    const float* __restrict__ enc_c, float* __restrict__ cbuf,
    unsigned short* __restrict__ xc0_0, unsigned short* __restrict__ xc0_1,
    unsigned short* __restrict__ xc1_0, unsigned short* __restrict__ hgen) {
  int idx = blockIdx.x * 256 + threadIdx.x;
  if (idx < 2 * B * H) {
    int l = idx >> 15, r = idx & 32767, b = r >> 10, hh = r & 1023;
    int half = hh >> 9, hr = hh & 511;
    int src = (2 * l + half) * B * (H / 2) + b * (H / 2) + hr;
    cbuf[idx] = enc_c[src];
    unsigned short hb = f2bf(enc_h[src]);
    if (l == 0) xc0_0[(size_t)b * K0 + KX + hh] = hb;
    else { xc1_0[(size_t)b * K1 + H + hh] = hb; hgen[(size_t)b * H + hh] = hb; }
  } else if (idx < 2 * B * H + 2 * B * 20) {
    int j = idx - 2 * B * H;
    int p = j / (B * 20), rr = j % (B * 20), b = rr / 20, kk = rr % 20;
    (p ? xc0_1 : xc0_0)[(size_t)b * K0 + KX + H + kk] = 0;
  }
}

// ===== one-time enc projection (f32 GEMM, bf16 out) ========================
__global__ __launch_bounds__(256) void k_encproj(const float* __restrict__ enc_out,
    const float* __restrict__ attn_W, const float* __restrict__ attn_b,
    unsigned short* __restrict__ encp) {
  __shared__ float As[16][66];
  __shared__ float Bs[16][66];
  int m0 = blockIdx.y * 64, n0 = blockIdx.x * 64;
  int tid = threadIdx.x, tx = tid & 15, ty = tid >> 4;
  float acc[4][4] = {};
  for (int k0 = 0; k0 < H; k0 += 16) {
#pragma unroll
    for (int i = 0; i < 4; i++) {
      int e = tid + i * 256, mm = e >> 4, kk = e & 15;
      As[kk][mm] = enc_out[(size_t)(m0 + mm) * H + k0 + kk];
      Bs[kk][mm] = attn_W[(size_t)(n0 + mm) * (2 * H) + H + k0 + kk];
    }
    __syncthreads();
#pragma unroll
    for (int kk = 0; kk < 16; kk++) {
      float a[4], bb[4];
#pragma unroll
      for (int i = 0; i < 4; i++) a[i] = As[kk][ty + 16 * i];
#pragma unroll
      for (int j = 0; j < 4; j++) bb[j] = Bs[kk][tx + 16 * j];
#pragma unroll
      for (int i = 0; i < 4; i++)
#pragma unroll
        for (int j = 0; j < 4; j++) acc[i][j] += a[i] * bb[j];
    }
    __syncthreads();
  }
#pragma unroll
  for (int i = 0; i < 4; i++) {
    int m = m0 + ty + 16 * i;
#pragma unroll
    for (int j = 0; j < 4; j++) {
      int n = n0 + tx + 16 * j;
      encp[(size_t)m * H + n] = f2bf(acc[i][j] + attn_b[n]);
    }
  }
}

// ===== MFMA GEMM core: 16 rows x 32 batch per wave =========================
template <int K>
DEVI void gemm_tile(const unsigned short* __restrict__ W, const unsigned short* __restrict__ X,
                    int m0w, int lane, f32x4& acc0, f32x4& acc1) {
  const unsigned short* Wp = W + (size_t)(m0w + (lane & 15)) * K + (lane >> 4) * 8;
  const unsigned short* Xp = X + (size_t)(lane & 15) * K + (lane >> 4) * 8;
#pragma unroll 4
  for (int k0 = 0; k0 < K; k0 += 32) {
    bf16x8 a  = *(const bf16x8*)(Wp + k0);
    bf16x8 b0 = *(const bf16x8*)(Xp + k0);
    bf16x8 b1 = *(const bf16x8*)(Xp + 16 * K + k0);
    acc0 = __builtin_amdgcn_mfma_f32_16x16x32_bf16(a, b0, acc0, 0, 0, 0);
    acc1 = __builtin_amdgcn_mfma_f32_16x16x32_bf16(a, b1, acc1, 0, 0, 0);
  }
}

// plain epilogue with row routing: rows < M0 -> out0 (+bias), else out1
template <int K>
__global__ __launch_bounds__(256) void k_gemm_out(const unsigned short* __restrict__ W,
    const unsigned short* __restrict__ X, const float* __restrict__ bias, int M0,
    float* __restrict__ out0, int ld0, float* __restrict__ out1, int ld1) {
  int wv = threadIdx.x >> 6, lane = threadIdx.x & 63;
  int m0w = blockIdx.x * 64 + wv * 16;
  f32x4 acc0 = {0.f, 0.f, 0.f, 0.f}, acc1 = acc0;
  gemm_tile<K>(W, X, m0w, lane, acc0, acc1);
  int r0 = m0w + (lane >> 4) * 4;
  int b = lane & 15;
  if (r0 < M0) {
    f32x4 bi = *(const f32x4*)&bias[r0];
    f32x4 o0 = acc0 + bi, o1 = acc1 + bi;
    *(f32x4*)&out0[(size_t)b * ld0 + r0] = o0;
    *(f32x4*)&out0[(size_t)(b + 16) * ld0 + r0] = o1;
  } else {
    int r = r0 - M0;
    *(f32x4*)&out1[(size_t)b * ld1 + r] = acc0;
    *(f32x4*)&out1[(size_t)(b + 16) * ld1 + r] = acc1;
  }
}

// LSTM epilogue: rows are n*4+g so lane's 4 regs = gates i,f,g,o of one (n,b)
template <int K>
__global__ __launch_bounds__(256) void k_gemm_lstm(const unsigned short* __restrict__ W,
    const unsigned short* __restrict__ X, const float* __restrict__ bcomb,
    float* __restrict__ c,
    unsigned short* __restrict__ hA, int ldA_, int offA,
    unsigned short* __restrict__ hB, int ldB_, int offB) {
  int wv = threadIdx.x >> 6, lane = threadIdx.x & 63;
  int m0w = blockIdx.x * 64 + wv * 16;
  f32x4 acc0 = {0.f, 0.f, 0.f, 0.f}, acc1 = acc0;
  gemm_tile<K>(W, X, m0w, lane, acc0, acc1);
  int r0 = m0w + (lane >> 4) * 4;
  int n = r0 >> 2;
  f32x4 bi = *(const f32x4*)&bcomb[r0];
#pragma unroll
  for (int f = 0; f < 2; f++) {
    f32x4 g = f ? acc1 : acc0;
    int b = (lane & 15) + f * 16;
    float gi = g[0] + bi[0], gf = g[1] + bi[1];
    float gg = g[2] + bi[2], go = g[3] + bi[3];
    float cp = c[(size_t)b * H + n];
    float c2 = sigm(gf) * cp + sigm(gi) * tanh_(gg);
    c[(size_t)b * H + n] = c2;
    unsigned short hb = f2bf(sigm(go) * tanh_(c2));
    hA[(size_t)b * ldA_ + offA + n] = hb;
    hB[(size_t)b * ldB_ + offB + n] = hb;
  }
}

// ===== attention scores ====================================================
__global__ __launch_bounds__(256) void k_scores(const unsigned short* __restrict__ encp,
    const float* __restrict__ hidproj, const float* __restrict__ vvec,
    float* __restrict__ scores) {
  int wid = blockIdx.x * 4 + (threadIdx.x >> 6);
  int lane = threadIdx.x & 63;
  int b = wid >> 9;
  const unsigned short* ep = encp + (size_t)wid * H;
  const float* hp = hidproj + (size_t)b * H;
  float acc = 0.f;
#pragma unroll
  for (int i = 0; i < 2; i++) {
    int base = i * 512 + lane * 8;
    uint4 u = *(const uint4*)&ep[base];
    float4 h0 = *(const float4*)&hp[base];
    float4 h1 = *(const float4*)&hp[base + 4];
    float4 v0 = *(const float4*)&vvec[base];
    float4 v1 = *(const float4*)&vvec[base + 4];
    acc += v0.x * tanh_(bf2f((unsigned short)(u.x & 0xffff)) + h0.x);
    acc += v0.y * tanh_(bf2f((unsigned short)(u.x >> 16)) + h0.y);
    acc += v0.z * tanh_(bf2f((unsigned short)(u.y & 0xffff)) + h0.z);
    acc += v0.w * tanh_(bf2f((unsigned short)(u.y >> 16)) + h0.w);
    acc += v1.x * tanh_(bf2f((unsigned short)(u.z & 0xffff)) + h1.x);
    acc += v1.y * tanh_(bf2f((unsigned short)(u.z >> 16)) + h1.y);
    acc += v1.z * tanh_(bf2f((unsigned short)(u.w & 0xffff)) + h1.z);
    acc += v1.w * tanh_(bf2f((unsigned short)(u.w >> 16)) + h1.w);
  }
#pragma unroll
  for (int off = 32; off; off >>= 1) acc += __shfl_xor(acc, off, 64);
  if (lane == 0) scores[wid] = acc;
}

// ===== softmax + ctx + embedding gather into xcat0 =========================
__global__ __launch_bounds__(256) void k_ctx(const float* __restrict__ scores,
    const unsigned short* __restrict__ enc_bf, const float* __restrict__ embedding,
    const int* __restrict__ question, int s, unsigned short* __restrict__ xc) {
  int b = blockIdx.x, y = blockIdx.y, tid = threadIdx.x;
  if (y == 16) {
    int tok = question[b * S + s];
    for (int e = tid; e < E; e += 256)
      xc[(size_t)b * K0 + e] = f2bf(embedding[(size_t)tok * E + e]);
    return;
  }
  __shared__ float aw[T];
  __shared__ float red[256];
  float s0 = scores[b * T + tid], s1 = scores[b * T + 256 + tid];
  float m = fmaxf(s0, s1);
  red[tid] = m; __syncthreads();
  for (int st = 128; st; st >>= 1) { if (tid < st) red[tid] = fmaxf(red[tid], red[tid + st]); __syncthreads(); }
  m = red[0]; __syncthreads();
  float e0 = __expf(s0 - m), e1 = __expf(s1 - m);
  aw[tid] = e0; aw[tid + 256] = e1;
  red[tid] = e0 + e1; __syncthreads();
  for (int st = 128; st; st >>= 1) { if (tid < st) red[tid] += red[tid + st]; __syncthreads(); }
  float inv = frcp(red[0]);
  __syncthreads();
  int wv = tid >> 6, l = tid & 63;
  int q = l & 15, tp = l >> 4;
  const unsigned short* eb = enc_bf + (size_t)b * T * H + y * 64 + q * 4;
  float a0 = 0.f, a1 = 0.f, a2 = 0.f, a3 = 0.f;
  for (int it = 0; it < 32; it++) {
    int t = it * 16 + wv * 4 + tp;
    uint2 u = *(const uint2*)&eb[(size_t)t * H];
    float w = aw[t];
    a0 += w * bf2f((unsigned short)(u.x & 0xffff));
    a1 += w * bf2f((unsigned short)(u.x >> 16));
    a2 += w * bf2f((unsigned short)(u.y & 0xffff));
    a3 += w * bf2f((unsigned short)(u.y >> 16));
  }
  a0 += __shfl_xor(a0, 16, 64); a0 += __shfl_xor(a0, 32, 64);
  a1 += __shfl_xor(a1, 16, 64); a1 += __shfl_xor(a1, 32, 64);
  a2 += __shfl_xor(a2, 16, 64); a2 += __shfl_xor(a2, 32, 64);
  a3 += __shfl_xor(a3, 16, 64); a3 += __shfl_xor(a3, 32, 64);
  __syncthreads();
  if (tp == 0) {
    red[wv * 64 + q * 4 + 0] = a0; red[wv * 64 + q * 4 + 1] = a1;
    red[wv * 64 + q * 4 + 2] = a2; red[wv * 64 + q * 4 + 3] = a3;
  }
  __syncthreads();
  if (tid < 64) {
    float val = (red[tid] + red[64 + tid] + red[128 + tid] + red[192 + tid]) * inv;
    xc[(size_t)b * K0 + E + y * 64 + tid] = f2bf(val);
  }
}

// ===== log-softmax: partial (B,8) then combine+write (B,8) =================
__global__ __launch_bounds__(256) void k_lsA(const float* __restrict__ logits,
                                             float* __restrict__ part) {
  int b = blockIdx.x, ch = blockIdx.y, tid = threadIdx.x;
  const float* L = logits + (size_t)b * V + ch * 4000;
  __shared__ float red[256];
  float m = -1e30f;
  for (int i = tid; i < 1000; i += 256) {
    float4 v = ((const float4*)L)[i];
    m = fmaxf(m, fmaxf(fmaxf(v.x, v.y), fmaxf(v.z, v.w)));
  }
  red[tid] = m; __syncthreads();
  for (int st = 128; st; st >>= 1) { if (tid < st) red[tid] = fmaxf(red[tid], red[tid + st]); __syncthreads(); }
  m = red[0]; __syncthreads();
  float ss = 0.f;
  for (int i = tid; i < 1000; i += 256) {
    float4 v = ((const float4*)L)[i];
    ss += __expf(v.x - m) + __expf(v.y - m) + __expf(v.z - m) + __expf(v.w - m);
  }
  red[tid] = ss; __syncthreads();
  for (int st = 128; st; st >>= 1) { if (tid < st) red[tid] += red[tid + st]; __syncthreads(); }
  if (tid == 0) { part[b * 16 + ch * 2] = m; part[b * 16 + ch * 2 + 1] = red[0]; }
}

__global__ __launch_bounds__(256) void k_lsB(const float* __restrict__ logits,
    const float* __restrict__ part, float* __restrict__ out, int s) {
  int b = blockIdx.x, ch = blockIdx.y, tid = threadIdx.x;
  float gm = -1e30f;
#pragma unroll
  for (int i = 0; i < 8; i++) gm = fmaxf(gm, part[b * 16 + i * 2]);
  float sum = 0.f;
#pragma unroll
  for (int i = 0; i < 8; i++) sum += part[b * 16 + i * 2 + 1] * __expf(part[b * 16 + i * 2] - gm);
  float lse = gm + __logf(sum);
  const float* L = logits + (size_t)b * V + ch * 4000;
  float* O = out + ((size_t)b * S + s) * V + ch * 4000;
  for (int i = tid; i < 1000; i += 256) {
    float4 v = ((const float4*)L)[i];
    ((float4*)O)[i] = make_float4(v.x - lse, v.y - lse, v.z - lse, v.w - lse);
  }
}

// ===========================================================================
extern "C" void kernel_launch(void* const* d_in, const int* in_sizes, int n_in,
                              void* d_out, int out_size, void* d_ws, size_t ws_size,
                              hipStream_t stream) {
  const float* enc_out   = (const float*)d_in[0];
  const float* enc_h     = (const float*)d_in[1];
  const float* enc_c     = (const float*)d_in[2];
  const float* embedding = (const float*)d_in[3];
  const float* attn_W    = (const float*)d_in[4];
  const float* attn_b    = (const float*)d_in[5];
  const float* vvec      = (const float*)d_in[6];
  const float* Wih0      = (const float*)d_in[7];
  const float* Whh0      = (const float*)d_in[8];
  const float* bih0      = (const float*)d_in[9];
  const float* bhh0      = (const float*)d_in[10];
  const float* Wih1      = (const float*)d_in[11];
  const float* Whh1      = (const float*)d_in[12];
  const float* bih1      = (const float*)d_in[13];
  const float* bhh1      = (const float*)d_in[14];
  const float* genW      = (const float*)d_in[15];
  const float* genb      = (const float*)d_in[16];
  const int*   question  = (const int*)d_in[17];
  float* out = (float*)d_out;

  char* w = (char*)d_ws;
  auto alloc = [&](size_t bytes) { char* r = w; w += (bytes + 255) & ~(size_t)255; return r; };
  unsigned short* Wbig  = (unsigned short*)alloc((size_t)MG * H * 2);
  unsigned short* Wc0   = (unsigned short*)alloc((size_t)4096 * K0 * 2);
  unsigned short* Wc1   = (unsigned short*)alloc((size_t)4096 * K1 * 2);
  unsigned short* encb  = (unsigned short*)alloc((size_t)B * T * H * 2);
  unsigned short* encp  = (unsigned short*)alloc((size_t)B * T * H * 2);
  float* bcomb0 = (float*)alloc(4096 * 4);
  float* bcomb1 = (float*)alloc(4096 * 4);
  float* cbuf   = (float*)alloc((size_t)2 * B * H * 4);
  unsigned short* xc0[2] = {(unsigned short*)alloc((size_t)B * K0 * 2),
                            (unsigned short*)alloc((size_t)B * K0 * 2)};
  unsigned short* xc1[2] = {(unsigned short*)alloc((size_t)B * K1 * 2),
                            (unsigned short*)alloc((size_t)B * K1 * 2)};
  unsigned short* hgen  = (unsigned short*)alloc((size_t)B * H * 2);
  float* hidproj = (float*)alloc((size_t)B * H * 4);
  float* scores  = (float*)alloc((size_t)B * T * 4);
  float* logits  = (float*)alloc((size_t)B * V * 4);
  float* lspart  = (float*)alloc((size_t)B * 16 * 4);

  // one-time prep
  k_cast_gen<<<MG * (H / 1024) * (1024 / 4) / 256 /* = 33024 */, 256, 0, stream>>>(genW, attn_W, Wbig);
  k_cast_l0<<<4096, 256, 0, stream>>>(Wih0, Whh0, Wc0);
  k_cast_l1<<<4096, 256, 0, stream>>>(Wih1, Whh1, Wc1);
  k_bias<<<32, 256, 0, stream>>>(bih0, bhh0, bih1, bhh1, bcomb0, bcomb1);
  k_cast_enc<<<(B * T * H / 4) / 256, 256, 0, stream>>>(enc_out, encb);
  k_init<<<(2 * B * H + 2 * B * 20 + 255) / 256, 256, 0, stream>>>(
      enc_h, enc_c, cbuf, xc0[0], xc0[1], xc1[0], hgen);
  k_encproj<<<dim3(H / 64, B * T / 64), 256, 0, stream>>>(enc_out, attn_W, attn_b, encp);
  // hidproj for step 0 from initial h1
  k_gemm_out<1024><<<H / 64, 256, 0, stream>>>(
      Wbig + (size_t)V * H, hgen, nullptr, 0, nullptr, 0, hidproj, H);

  for (int s = 0; s < S; s++) {
    int par = s & 1;
    k_scores<<<B * T / 4, 256, 0, stream>>>(encp, hidproj, vvec, scores);
    k_ctx<<<dim3(B, 17), 256, 0, stream>>>(scores, encb, embedding, question, s, xc0[par]);
    k_gemm_lstm<K0><<<4096 / 64, 256, 0, stream>>>(
        Wc0, xc0[par], bcomb0, cbuf,
        xc0[par ^ 1], K0, KX,        // h0n -> next step's layer-0 recurrent slot
        xc1[par], K1, 0);            // h0n -> layer-1 input slot (this step)
    k_gemm_lstm<K1><<<4096 / 64, 256, 0, stream>>>(
        Wc1, xc1[par], bcomb1, cbuf + B * H,
        xc1[par ^ 1], K1, H,         // h1n -> next step's layer-1 recurrent slot
        hgen, H, 0);                 // h1n -> generator/hidproj input
    k_gemm_out<1024><<<MG / 64, 256, 0, stream>>>(
        Wbig, hgen, genb, V, logits, V, hidproj, H);
    k_lsA<<<dim3(B, 8), 256, 0, stream>>>(logits, lspart);
    k_lsB<<<dim3(B, 8), 256, 0, stream>>>(logits, lspart, out, s);
  }
}

// Round 3
// 4096.397 us; speedup vs baseline: 4.1684x; 1.5241x over previous
//
#include <hip/hip_runtime.h>
#include <hip/hip_bf16.h>
#include <math.h>

#define DEVI static __device__ __forceinline__

namespace {
constexpr int B = 32, T = 512, H = 1024, E = 300, V = 32000, S = 50;
constexpr int KX = E + H;       // 1324
constexpr int K0 = 2368;        // KX + H + 20 zero-pad  (74 * 32)
constexpr int K1 = 2048;        // H + H                 (64 * 32)
constexpr int MG = V + H;       // 33024 = generator rows + attn-left rows
}

typedef __bf16 bf16x8 __attribute__((ext_vector_type(8)));
typedef float f32x4 __attribute__((ext_vector_type(4)));

DEVI float bf2f(unsigned short u) { union { unsigned int i; float f; } v; v.i = (unsigned int)u << 16; return v.f; }
DEVI unsigned short f2bf(float f) {
  union { float f; unsigned int i; } v; v.f = f;
  unsigned int x = v.i;
  return (unsigned short)((x + 0x7fffu + ((x >> 16) & 1u)) >> 16);
}
#if __has_builtin(__builtin_amdgcn_rcpf)
DEVI float frcp(float x) { return __builtin_amdgcn_rcpf(x); }
#else
DEVI float frcp(float x) { return 1.0f / x; }
#endif
DEVI float sigm(float x) { return frcp(1.0f + __expf(-x)); }
DEVI float tanh_(float x) { return 1.0f - 2.0f * frcp(__expf(2.0f * x) + 1.0f); }

// ===== one-time weight casts ==============================================
__global__ __launch_bounds__(256) void k_cast_gen(const float* __restrict__ genW,
    const float* __restrict__ attn_W, unsigned short* __restrict__ Wbig) {
  size_t i4 = ((size_t)blockIdx.x * 256 + threadIdx.x) * 4;
  if (i4 >= (size_t)MG * H) return;
  int row = (int)(i4 >> 10), k = (int)(i4 & 1023);
  const float* src = row < V ? &genW[((size_t)row << 10) + k]
                             : &attn_W[(size_t)(row - V) * (2 * H) + k];
  float4 v = *(const float4*)src;
  ushort4 o; o.x = f2bf(v.x); o.y = f2bf(v.y); o.z = f2bf(v.z); o.w = f2bf(v.w);
  *(ushort4*)&Wbig[i4] = o;
}

__global__ __launch_bounds__(256) void k_cast_l0(const float* __restrict__ Wih,
    const float* __restrict__ Whh, unsigned short* __restrict__ Wc) {
  int m = blockIdx.x;                       // 4096 rows, m = n*4 + g
  int g = m & 3, n = m >> 2, srow = g * H + n;
  for (int i = threadIdx.x; i < K0 / 4; i += 256) {
    int k = i * 4;
    float4 v;
    if (k < KX) v = *(const float4*)&Wih[(size_t)srow * KX + k];
    else if (k < KX + H) v = *(const float4*)&Whh[(size_t)srow * H + (k - KX)];
    else v = make_float4(0.f, 0.f, 0.f, 0.f);
    ushort4 o; o.x = f2bf(v.x); o.y = f2bf(v.y); o.z = f2bf(v.z); o.w = f2bf(v.w);
    *(ushort4*)&Wc[(size_t)m * K0 + k] = o;
  }
}

__global__ __launch_bounds__(256) void k_cast_l1(const float* __restrict__ Wih,
    const float* __restrict__ Whh, unsigned short* __restrict__ Wc) {
  int m = blockIdx.x;
  int g = m & 3, n = m >> 2, srow = g * H + n;
  for (int i = threadIdx.x; i < K1 / 4; i += 256) {
    int k = i * 4;
    float4 v = (k < H) ? *(const float4*)&Wih[(size_t)srow * H + k]
                       : *(const float4*)&Whh[(size_t)srow * H + (k - H)];
    ushort4 o; o.x = f2bf(v.x); o.y = f2bf(v.y); o.z = f2bf(v.z); o.w = f2bf(v.w);
    *(ushort4*)&Wc[(size_t)m * K1 + k] = o;
  }
}

__global__ __launch_bounds__(256) void k_cast_attnr(const float* __restrict__ attn_W,
                                                    unsigned short* __restrict__ Wr) {
  size_t i4 = ((size_t)blockIdx.x * 256 + threadIdx.x) * 4;
  if (i4 >= (size_t)H * H) return;
  int n = (int)(i4 >> 10), k = (int)(i4 & 1023);
  float4 v = *(const float4*)&attn_W[(size_t)n * (2 * H) + H + k];
  ushort4 o; o.x = f2bf(v.x); o.y = f2bf(v.y); o.z = f2bf(v.z); o.w = f2bf(v.w);
  *(ushort4*)&Wr[i4] = o;
}

__global__ void k_bias(const float* bih0, const float* bhh0,
                       const float* bih1, const float* bhh1,
                       float* bc0, float* bc1) {
  int idx = blockIdx.x * 256 + threadIdx.x;
  if (idx < 4096) { int g = idx & 3, n = idx >> 2; bc0[idx] = bih0[g * H + n] + bhh0[g * H + n]; }
  else if (idx < 8192) { int m = idx - 4096; int g = m & 3, n = m >> 2; bc1[m] = bih1[g * H + n] + bhh1[g * H + n]; }
}

__global__ __launch_bounds__(256) void k_cast_enc(const float* __restrict__ src,
                                                  unsigned short* __restrict__ dst) {
  size_t i4 = ((size_t)blockIdx.x * 256 + threadIdx.x) * 4;
  if (i4 >= (size_t)B * T * H) return;
  float4 v = *(const float4*)&src[i4];
  ushort4 o; o.x = f2bf(v.x); o.y = f2bf(v.y); o.z = f2bf(v.z); o.w = f2bf(v.w);
  *(ushort4*)&dst[i4] = o;
}

// ===== initial state =======================================================
__global__ __launch_bounds__(256) void k_init(const float* __restrict__ enc_h,
    const float* __restrict__ enc_c, float* __restrict__ cbuf,
    unsigned short* __restrict__ xc0_0, unsigned short* __restrict__ xc0_1,
    unsigned short* __restrict__ xc1_0, unsigned short* __restrict__ hgen) {
  int idx = blockIdx.x * 256 + threadIdx.x;
  if (idx < 2 * B * H) {
    int l = idx >> 15, r = idx & 32767, b = r >> 10, hh = r & 1023;
    int half = hh >> 9, hr = hh & 511;
    int src = (2 * l + half) * B * (H / 2) + b * (H / 2) + hr;
    cbuf[idx] = enc_c[src];
    unsigned short hb = f2bf(enc_h[src]);
    if (l == 0) xc0_0[(size_t)b * K0 + KX + hh] = hb;
    else { xc1_0[(size_t)b * K1 + H + hh] = hb; hgen[(size_t)b * H + hh] = hb; }
  } else if (idx < 2 * B * H + 2 * B * 20) {
    int j = idx - 2 * B * H;
    int p = j / (B * 20), rr = j % (B * 20), b = rr / 20, kk = rr % 20;
    (p ? xc0_1 : xc0_0)[(size_t)b * K0 + KX + H + kk] = 0;
  }
}

// ===== one-time enc projection: MFMA bf16 GEMM =============================
// encp[m][n] = bf16( sum_k encb[m][k]*Wr[n][k] + attn_b[n] )
// block: 64 n (4 waves x 16) x 64 m (4 acc groups); grid (H/64, B*T/64)
__global__ __launch_bounds__(256) void k_encproj_mfma(const unsigned short* __restrict__ Wr,
    const unsigned short* __restrict__ Xb, const float* __restrict__ attn_b,
    unsigned short* __restrict__ encp) {
  int wv = threadIdx.x >> 6, lane = threadIdx.x & 63;
  int n0w = blockIdx.x * 64 + wv * 16;
  int m0 = blockIdx.y * 64;
  const unsigned short* Wp = Wr + (size_t)(n0w + (lane & 15)) * H + (lane >> 4) * 8;
  const unsigned short* Xp = Xb + (size_t)(m0 + (lane & 15)) * H + (lane >> 4) * 8;
  f32x4 acc[4] = {{0.f,0.f,0.f,0.f},{0.f,0.f,0.f,0.f},{0.f,0.f,0.f,0.f},{0.f,0.f,0.f,0.f}};
#pragma unroll 2
  for (int k0 = 0; k0 < H; k0 += 32) {
    bf16x8 a = *(const bf16x8*)(Wp + k0);
#pragma unroll
    for (int g = 0; g < 4; g++) {
      bf16x8 b = *(const bf16x8*)(Xp + (size_t)g * 16 * H + k0);
      acc[g] = __builtin_amdgcn_mfma_f32_16x16x32_bf16(a, b, acc[g], 0, 0, 0);
    }
  }
  int nb = n0w + (lane >> 4) * 4;
  f32x4 bi = *(const f32x4*)&attn_b[nb];
#pragma unroll
  for (int g = 0; g < 4; g++) {
    int m = m0 + g * 16 + (lane & 15);
    f32x4 o = acc[g] + bi;
    ushort4 ob; ob.x = f2bf(o[0]); ob.y = f2bf(o[1]); ob.z = f2bf(o[2]); ob.w = f2bf(o[3]);
    *(ushort4*)&encp[(size_t)m * H + nb] = ob;
  }
}

// ===== MFMA GEMM core: 16 rows x 32 batch per wave =========================
template <int K>
DEVI void gemm_tile(const unsigned short* __restrict__ W, const unsigned short* __restrict__ X,
                    int m0w, int lane, f32x4& acc0, f32x4& acc1) {
  const unsigned short* Wp = W + (size_t)(m0w + (lane & 15)) * K + (lane >> 4) * 8;
  const unsigned short* Xp = X + (size_t)(lane & 15) * K + (lane >> 4) * 8;
#pragma unroll 4
  for (int k0 = 0; k0 < K; k0 += 32) {
    bf16x8 a  = *(const bf16x8*)(Wp + k0);
    bf16x8 b0 = *(const bf16x8*)(Xp + k0);
    bf16x8 b1 = *(const bf16x8*)(Xp + 16 * K + k0);
    acc0 = __builtin_amdgcn_mfma_f32_16x16x32_bf16(a, b0, acc0, 0, 0, 0);
    acc1 = __builtin_amdgcn_mfma_f32_16x16x32_bf16(a, b1, acc1, 0, 0, 0);
  }
}

// generator GEMM: rows < M0 -> logits (+bias, + per-block expsum partials),
// rows >= M0 -> hidproj. part==nullptr disables the expsum path.
template <int K>
__global__ __launch_bounds__(256) void k_gemm_out(const unsigned short* __restrict__ W,
    const unsigned short* __restrict__ X, const float* __restrict__ bias, int M0,
    float* __restrict__ out0, int ld0, float* __restrict__ out1, int ld1,
    float* __restrict__ part) {
  __shared__ float esum[4][32];
  int wv = threadIdx.x >> 6, lane = threadIdx.x & 63;
  int m0w = blockIdx.x * 64 + wv * 16;
  f32x4 acc0 = {0.f, 0.f, 0.f, 0.f}, acc1 = acc0;
  gemm_tile<K>(W, X, m0w, lane, acc0, acc1);
  int r0 = m0w + (lane >> 4) * 4;
  int b = lane & 15;
  float s0 = 0.f, s1 = 0.f;
  if (r0 < M0) {
    f32x4 bi = *(const f32x4*)&bias[r0];
    f32x4 o0 = acc0 + bi, o1 = acc1 + bi;
    *(f32x4*)&out0[(size_t)b * ld0 + r0] = o0;
    *(f32x4*)&out0[(size_t)(b + 16) * ld0 + r0] = o1;
    s0 = __expf(o0[0]) + __expf(o0[1]) + __expf(o0[2]) + __expf(o0[3]);
    s1 = __expf(o1[0]) + __expf(o1[1]) + __expf(o1[2]) + __expf(o1[3]);
  } else {
    int r = r0 - M0;
    *(f32x4*)&out1[(size_t)b * ld1 + r] = acc0;
    *(f32x4*)&out1[(size_t)(b + 16) * ld1 + r] = acc1;
  }
  if (part != nullptr && blockIdx.x < V / 64) {
    s0 += __shfl_xor(s0, 16, 64); s0 += __shfl_xor(s0, 32, 64);
    s1 += __shfl_xor(s1, 16, 64); s1 += __shfl_xor(s1, 32, 64);
    if (lane < 16) { esum[wv][lane] = s0; esum[wv][lane + 16] = s1; }
    __syncthreads();
    if (threadIdx.x < 32)
      part[blockIdx.x * 32 + threadIdx.x] =
          esum[0][threadIdx.x] + esum[1][threadIdx.x] + esum[2][threadIdx.x] + esum[3][threadIdx.x];
  }
}

// LSTM: 16 rows/block, 4 waves split K (interleaved 32-chunks), LDS reduce.
// rows are n*4+g so lane's 4 accs = gates i,f,g,o of one (n,b).
template <int K>
__global__ __launch_bounds__(256) void k_gemm_lstm(const unsigned short* __restrict__ W,
    const unsigned short* __restrict__ X, const float* __restrict__ bcomb,
    float* __restrict__ c,
    unsigned short* __restrict__ hA, int ldA_, int offA,
    unsigned short* __restrict__ hB, int ldB_, int offB) {
  __shared__ f32x4 red[4][64][2];
  int wv = threadIdx.x >> 6, lane = threadIdx.x & 63;
  int m0w = blockIdx.x * 16;
  const unsigned short* Wp = W + (size_t)(m0w + (lane & 15)) * K + (lane >> 4) * 8;
  const unsigned short* Xp = X + (size_t)(lane & 15) * K + (lane >> 4) * 8;
  f32x4 acc0 = {0.f, 0.f, 0.f, 0.f}, acc1 = acc0;
#pragma unroll 2
  for (int k0 = wv * 32; k0 < K; k0 += 128) {
    bf16x8 a  = *(const bf16x8*)(Wp + k0);
    bf16x8 b0 = *(const bf16x8*)(Xp + k0);
    bf16x8 b1 = *(const bf16x8*)(Xp + 16 * K + k0);
    acc0 = __builtin_amdgcn_mfma_f32_16x16x32_bf16(a, b0, acc0, 0, 0, 0);
    acc1 = __builtin_amdgcn_mfma_f32_16x16x32_bf16(a, b1, acc1, 0, 0, 0);
  }
  red[wv][lane][0] = acc0;
  red[wv][lane][1] = acc1;
  __syncthreads();
  if (wv == 0) {
    acc0 = red[0][lane][0] + red[1][lane][0] + red[2][lane][0] + red[3][lane][0];
    acc1 = red[0][lane][1] + red[1][lane][1] + red[2][lane][1] + red[3][lane][1];
    int r0 = m0w + (lane >> 4) * 4;
    int n = r0 >> 2;
    f32x4 bi = *(const f32x4*)&bcomb[r0];
#pragma unroll
    for (int f = 0; f < 2; f++) {
      f32x4 g = f ? acc1 : acc0;
      int b = (lane & 15) + f * 16;
      float gi = g[0] + bi[0], gf = g[1] + bi[1];
      float gg = g[2] + bi[2], go = g[3] + bi[3];
      float cp = c[(size_t)b * H + n];
      float c2 = sigm(gf) * cp + sigm(gi) * tanh_(gg);
      c[(size_t)b * H + n] = c2;
      unsigned short hb = f2bf(sigm(go) * tanh_(c2));
      hA[(size_t)b * ldA_ + offA + n] = hb;
      hB[(size_t)b * ldB_ + offB + n] = hb;
    }
  }
}

// ===== attention scores ====================================================
__global__ __launch_bounds__(256) void k_scores(const unsigned short* __restrict__ encp,
    const float* __restrict__ hidproj, const float* __restrict__ vvec,
    float* __restrict__ scores) {
  int wid = blockIdx.x * 4 + (threadIdx.x >> 6);
  int lane = threadIdx.x & 63;
  int b = wid >> 9;
  const unsigned short* ep = encp + (size_t)wid * H;
  const float* hp = hidproj + (size_t)b * H;
  float acc = 0.f;
#pragma unroll
  for (int i = 0; i < 2; i++) {
    int base = i * 512 + lane * 8;
    uint4 u = *(const uint4*)&ep[base];
    float4 h0 = *(const float4*)&hp[base];
    float4 h1 = *(const float4*)&hp[base + 4];
    float4 v0 = *(const float4*)&vvec[base];
    float4 v1 = *(const float4*)&vvec[base + 4];
    acc += v0.x * tanh_(bf2f((unsigned short)(u.x & 0xffff)) + h0.x);
    acc += v0.y * tanh_(bf2f((unsigned short)(u.x >> 16)) + h0.y);
    acc += v0.z * tanh_(bf2f((unsigned short)(u.y & 0xffff)) + h0.z);
    acc += v0.w * tanh_(bf2f((unsigned short)(u.y >> 16)) + h0.w);
    acc += v1.x * tanh_(bf2f((unsigned short)(u.z & 0xffff)) + h1.x);
    acc += v1.y * tanh_(bf2f((unsigned short)(u.z >> 16)) + h1.y);
    acc += v1.z * tanh_(bf2f((unsigned short)(u.w & 0xffff)) + h1.z);
    acc += v1.w * tanh_(bf2f((unsigned short)(u.w >> 16)) + h1.w);
  }
#pragma unroll
  for (int off = 32; off; off >>= 1) acc += __shfl_xor(acc, off, 64);
  if (lane == 0) scores[wid] = acc;
}

// ===== softmax + ctx + embedding gather into xcat0 =========================
__global__ __launch_bounds__(256) void k_ctx(const float* __restrict__ scores,
    const unsigned short* __restrict__ enc_bf, const float* __restrict__ embedding,
    const int* __restrict__ question, int s, unsigned short* __restrict__ xc) {
  int b = blockIdx.x, y = blockIdx.y, tid = threadIdx.x;
  if (y == 16) {
    int tok = question[b * S + s];
    for (int e = tid; e < E; e += 256)
      xc[(size_t)b * K0 + e] = f2bf(embedding[(size_t)tok * E + e]);
    return;
  }
  __shared__ float aw[T];
  __shared__ float red[256];
  float s0 = scores[b * T + tid], s1 = scores[b * T + 256 + tid];
  float m = fmaxf(s0, s1);
  red[tid] = m; __syncthreads();
  for (int st = 128; st; st >>= 1) { if (tid < st) red[tid] = fmaxf(red[tid], red[tid + st]); __syncthreads(); }
  m = red[0]; __syncthreads();
  float e0 = __expf(s0 - m), e1 = __expf(s1 - m);
  aw[tid] = e0; aw[tid + 256] = e1;
  red[tid] = e0 + e1; __syncthreads();
  for (int st = 128; st; st >>= 1) { if (tid < st) red[tid] += red[tid + st]; __syncthreads(); }
  float inv = frcp(red[0]);
  __syncthreads();
  int wv = tid >> 6, l = tid & 63;
  int q = l & 15, tp = l >> 4;
  const unsigned short* eb = enc_bf + (size_t)b * T * H + y * 64 + q * 4;
  float a0 = 0.f, a1 = 0.f, a2 = 0.f, a3 = 0.f;
  for (int it = 0; it < 32; it++) {
    int t = it * 16 + wv * 4 + tp;
    uint2 u = *(const uint2*)&eb[(size_t)t * H];
    float w = aw[t];
    a0 += w * bf2f((unsigned short)(u.x & 0xffff));
    a1 += w * bf2f((unsigned short)(u.x >> 16));
    a2 += w * bf2f((unsigned short)(u.y & 0xffff));
    a3 += w * bf2f((unsigned short)(u.y >> 16));
  }
  a0 += __shfl_xor(a0, 16, 64); a0 += __shfl_xor(a0, 32, 64);
  a1 += __shfl_xor(a1, 16, 64); a1 += __shfl_xor(a1, 32, 64);
  a2 += __shfl_xor(a2, 16, 64); a2 += __shfl_xor(a2, 32, 64);
  a3 += __shfl_xor(a3, 16, 64); a3 += __shfl_xor(a3, 32, 64);
  __syncthreads();
  if (tp == 0) {
    red[wv * 64 + q * 4 + 0] = a0; red[wv * 64 + q * 4 + 1] = a1;
    red[wv * 64 + q * 4 + 2] = a2; red[wv * 64 + q * 4 + 3] = a3;
  }
  __syncthreads();
  if (tid < 64) {
    float val = (red[tid] + red[64 + tid] + red[128 + tid] + red[192 + tid]) * inv;
    xc[(size_t)b * K0 + E + y * 64 + tid] = f2bf(val);
  }
}

// ===== log-softmax finalize: lse from partials, subtract + write ===========
__global__ __launch_bounds__(256) void k_lsB(const float* __restrict__ logits,
    const float* __restrict__ part, float* __restrict__ out, int s) {
  int b = blockIdx.x, ch = blockIdx.y, tid = threadIdx.x;
  __shared__ float red[256];
  float ssum = 0.f;
  for (int i = tid; i < V / 64; i += 256) ssum += part[i * 32 + b];
  red[tid] = ssum; __syncthreads();
  for (int st = 128; st; st >>= 1) { if (tid < st) red[tid] += red[tid + st]; __syncthreads(); }
  float lse = __logf(red[0]);
  const float* L = logits + (size_t)b * V + ch * 4000;
  float* O = out + ((size_t)b * S + s) * V + ch * 4000;
  for (int i = tid; i < 1000; i += 256) {
    float4 v = ((const float4*)L)[i];
    ((float4*)O)[i] = make_float4(v.x - lse, v.y - lse, v.z - lse, v.w - lse);
  }
}

// ===========================================================================
extern "C" void kernel_launch(void* const* d_in, const int* in_sizes, int n_in,
                              void* d_out, int out_size, void* d_ws, size_t ws_size,
                              hipStream_t stream) {
  const float* enc_out   = (const float*)d_in[0];
  const float* enc_h     = (const float*)d_in[1];
  const float* enc_c     = (const float*)d_in[2];
  const float* embedding = (const float*)d_in[3];
  const float* attn_W    = (const float*)d_in[4];
  const float* attn_b    = (const float*)d_in[5];
  const float* vvec      = (const float*)d_in[6];
  const float* Wih0      = (const float*)d_in[7];
  const float* Whh0      = (const float*)d_in[8];
  const float* bih0      = (const float*)d_in[9];
  const float* bhh0      = (const float*)d_in[10];
  const float* Wih1      = (const float*)d_in[11];
  const float* Whh1      = (const float*)d_in[12];
  const float* bih1      = (const float*)d_in[13];
  const float* bhh1      = (const float*)d_in[14];
  const float* genW      = (const float*)d_in[15];
  const float* genb      = (const float*)d_in[16];
  const int*   question  = (const int*)d_in[17];
  float* out = (float*)d_out;

  char* w = (char*)d_ws;
  auto alloc = [&](size_t bytes) { char* r = w; w += (bytes + 255) & ~(size_t)255; return r; };
  unsigned short* Wbig  = (unsigned short*)alloc((size_t)MG * H * 2);
  unsigned short* Wc0   = (unsigned short*)alloc((size_t)4096 * K0 * 2);
  unsigned short* Wc1   = (unsigned short*)alloc((size_t)4096 * K1 * 2);
  unsigned short* encb  = (unsigned short*)alloc((size_t)B * T * H * 2);
  unsigned short* encp  = (unsigned short*)alloc((size_t)B * T * H * 2);
  unsigned short* Wr    = (unsigned short*)alloc((size_t)H * H * 2);
  float* bcomb0 = (float*)alloc(4096 * 4);
  float* bcomb1 = (float*)alloc(4096 * 4);
  float* cbuf   = (float*)alloc((size_t)2 * B * H * 4);
  unsigned short* xc0[2] = {(unsigned short*)alloc((size_t)B * K0 * 2),
                            (unsigned short*)alloc((size_t)B * K0 * 2)};
  unsigned short* xc1[2] = {(unsigned short*)alloc((size_t)B * K1 * 2),
                            (unsigned short*)alloc((size_t)B * K1 * 2)};
  unsigned short* hgen  = (unsigned short*)alloc((size_t)B * H * 2);
  float* hidproj = (float*)alloc((size_t)B * H * 4);
  float* scores  = (float*)alloc((size_t)B * T * 4);
  float* logits  = (float*)alloc((size_t)B * V * 4);
  float* part    = (float*)alloc((size_t)(V / 64) * 32 * 4);

  // one-time prep
  k_cast_gen<<<(int)(((size_t)MG * H / 4 + 255) / 256), 256, 0, stream>>>(genW, attn_W, Wbig);
  k_cast_l0<<<4096, 256, 0, stream>>>(Wih0, Whh0, Wc0);
  k_cast_l1<<<4096, 256, 0, stream>>>(Wih1, Whh1, Wc1);
  k_cast_attnr<<<H * H / 4 / 256, 256, 0, stream>>>(attn_W, Wr);
  k_bias<<<32, 256, 0, stream>>>(bih0, bhh0, bih1, bhh1, bcomb0, bcomb1);
  k_cast_enc<<<(B * T * H / 4) / 256, 256, 0, stream>>>(enc_out, encb);
  k_init<<<(2 * B * H + 2 * B * 20 + 255) / 256, 256, 0, stream>>>(
      enc_h, enc_c, cbuf, xc0[0], xc0[1], xc1[0], hgen);
  k_encproj_mfma<<<dim3(H / 64, B * T / 64), 256, 0, stream>>>(Wr, encb, attn_b, encp);
  // hidproj for step 0 from initial h1
  k_gemm_out<1024><<<H / 64, 256, 0, stream>>>(
      Wbig + (size_t)V * H, hgen, nullptr, 0, nullptr, 0, hidproj, H, nullptr);

  for (int s = 0; s < S; s++) {
    int par = s & 1;
    k_scores<<<B * T / 4, 256, 0, stream>>>(encp, hidproj, vvec, scores);
    k_ctx<<<dim3(B, 17), 256, 0, stream>>>(scores, encb, embedding, question, s, xc0[par]);
    k_gemm_lstm<K0><<<4096 / 16, 256, 0, stream>>>(
        Wc0, xc0[par], bcomb0, cbuf,
        xc0[par ^ 1], K0, KX,        // h0n -> next step's layer-0 recurrent slot
        xc1[par], K1, 0);            // h0n -> layer-1 input slot (this step)
    k_gemm_lstm<K1><<<4096 / 16, 256, 0, stream>>>(
        Wc1, xc1[par], bcomb1, cbuf + B * H,
        xc1[par ^ 1], K1, H,         // h1n -> next step's layer-1 recurrent slot
        hgen, H, 0);                 // h1n -> generator/hidproj input
    k_gemm_out<1024><<<MG / 64, 256, 0, stream>>>(
        Wbig, hgen, genb, V, logits, V, hidproj, H, part);
    k_lsB<<<dim3(B, 8), 256, 0, stream>>>(logits, part, out, s);
  }
}